// Round 2
// baseline (356.110 us; speedup 1.0000x reference)
//
#include <hip/hip_runtime.h>

// Problem: B=16384, F=1024, H=64, D=256, TE=CE=4.
// I/O dtype: float32 (per reference). Internal compute: fp16 MFMA, fp32 accum.
// out = (outA, outS, outB), each [B, 256] fp32, concatenated in d_out.
//
// R2: FUSED l1+l2. R1 showed the two-kernel structure is latency-bound with a
// ~50MB hbuf HBM round-trip and ~100us of inter-kernel overhead. New design:
// 256 blocks x 512 threads (1 block/CU), each block owns 64 rows end-to-end.
// h[3][64][256] f16 lives in LDS (never HBM); gate logits in regs, softmax
// in-block; W2 staged from L2. x prefetch distance 2 (HBM ~900cy), W1/gate
// distance 1 (L2-hot), uniform per-wave issue counts -> single vmcnt(5).

#define BB 16384
#define FF 1024

typedef _Float16 f16;
typedef __fp16 h16x2 __attribute__((ext_vector_type(2)));   // cvt_pkrtz return type
typedef _Float16 f16x8 __attribute__((ext_vector_type(8)));
typedef float f32x4 __attribute__((ext_vector_type(4)));

// async global->LDS, 16B per lane. LDS dest must be wave-uniform base + lane*16.
__device__ __forceinline__ void load_lds16(const void* g, void* l) {
    __builtin_amdgcn_global_load_lds(
        (const __attribute__((address_space(1))) unsigned int*)g,
        (__attribute__((address_space(3))) unsigned int*)l, 16, 0, 0);
}

__device__ __forceinline__ f16x8 pack8(float4 lo, float4 hi) {
    union { f16x8 v; h16x2 p[4]; } u;
    u.p[0] = __builtin_amdgcn_cvt_pkrtz(lo.x, lo.y);
    u.p[1] = __builtin_amdgcn_cvt_pkrtz(lo.z, lo.w);
    u.p[2] = __builtin_amdgcn_cvt_pkrtz(hi.x, hi.y);
    u.p[3] = __builtin_amdgcn_cvt_pkrtz(hi.z, hi.w);
    return u.v;
}

// ---------------------------------------------------------------------------
// Pack: Wp[g][c][k] = (f16)W1g[e=c>>6][k][h=c&63]     (3 x 256 x 1024)
//       W2T[g][e][d][h] = (f16)W2g[e][h][d]           (3 x 4 x 256 x 64)
//       Gp[g][c][k]  = (f16)Wgg[k][c] (zero-pad c>=ng) (3 x 16 x 1024)
// ---------------------------------------------------------------------------
__global__ __launch_bounds__(256) void pack_kernel(
    const float* __restrict__ W1A, const float* __restrict__ W1S, const float* __restrict__ W1B,
    const float* __restrict__ W2A, const float* __restrict__ W2S, const float* __restrict__ W2B,
    const float* __restrict__ WgA, const float* __restrict__ WgS, const float* __restrict__ WgB,
    f16* __restrict__ Wp, f16* __restrict__ W2T, f16* __restrict__ Gp)
{
    int idx = blockIdx.x * 256 + threadIdx.x;
    if (idx < 786432) {
        int g = idx / 262144, rem = idx % 262144;
        int c = rem >> 10, k = rem & 1023;
        const float* W1 = (g == 0) ? W1A : ((g == 1) ? W1S : W1B);
        Wp[idx] = (f16)W1[((c >> 6) << 16) + k * 64 + (c & 63)];
    } else if (idx < 983040) {
        int j = idx - 786432;
        int g = j / 65536, rem = j % 65536;
        int e = rem >> 14, rr = rem & 16383;
        int d = rr >> 6, hh = rr & 63;
        const float* W2 = (g == 0) ? W2A : ((g == 1) ? W2S : W2B);
        W2T[j] = (f16)W2[e * 16384 + hh * 256 + d];
    } else {
        int j = idx - 983040;                 // < 3*16384
        int g = j / 16384, rem = j % 16384;
        int c = rem >> 10, k = rem & 1023;    // Gp[g][c][k]
        int ng = (g == 1) ? 12 : 8;
        const float* Wg = (g == 0) ? WgA : ((g == 1) ? WgS : WgB);
        Gp[j] = (c < ng) ? (f16)Wg[k * ng + c] : (f16)0.0f;
    }
}

// ---------------------------------------------------------------------------
// Fused kernel. grid 256, block 512 (8 waves), dynamic LDS 159744 B.
//
// LDS map:
//  [0, 98304)          h[3][64][256] f16, col-swizzled: col' = col ^ ((row&7)<<3)
//  [98304, 157696)     stage region (59392 B):
//     l1 : Xs[3][64x32 f32]  @ +0      (3 x 8192)
//          Ws[2][256x32 f16] @ +24576  (2 x 16384)
//     l2 : W2s[2][128x64 f16] @ +0     (2 x 16384)
//          b2s[3][1024] f32   @ +32768 (12288)
//          gsh[64][28] f32    @ +45056 (7168)   (gA 0-7 | gS 8-19 | gB 20-27)
//  [157696, 159744)    Gs[2][16x32 f16] gate-weight k-tiles (dbuf)
// ---------------------------------------------------------------------------
__global__ __launch_bounds__(512, 2) void fused_kernel(
    const float* __restrict__ xA, const float* __restrict__ xS, const float* __restrict__ xB,
    const float* __restrict__ b1A, const float* __restrict__ b1S, const float* __restrict__ b1B,
    const float* __restrict__ bgA, const float* __restrict__ bgS, const float* __restrict__ bgB,
    const float* __restrict__ b2A, const float* __restrict__ b2S, const float* __restrict__ b2B,
    const f16* __restrict__ Wp,      // [3][256][1024]
    const f16* __restrict__ Gp,      // [3][16][1024]
    const f16* __restrict__ W2T,     // [3][4][256][64]
    float* __restrict__ out)         // [3][B][256]
{
    extern __shared__ char smem[];
    f16*   hls   = (f16*)smem;                     // [3][64][256]
    char*  stage = smem + 98304;
    float* Xs    = (float*)stage;                  // l1: [3][2048]
    f16*   Ws    = (f16*)(stage + 24576);          // l1: [2][8192]
    f16*   W2s   = (f16*)stage;                    // l2: [2][8192]
    float* b2s   = (float*)(stage + 32768);        // l2: [3][1024]
    float* gsh   = (float*)(stage + 45056);        // l2: [64][28]
    f16*   Gs    = (f16*)(smem + 157696);          // [2][512]

    const int tid  = threadIdx.x;
    const int lane = tid & 63;
    const int w    = tid >> 6;
    const int lrow = lane & 15;
    const int quad = lane >> 4;
    const int row0 = blockIdx.x * 64;

    // l1 wave tile: 8 waves = 2 row-halves(32) x 4 col-quarters(64)
    const int wm = (w >> 2) * 32;
    const int wn = (w & 3) * 64;
    // l2 wave tile: 8 waves = 4 row-blocks(16) x 2 d-halves(64) of the 128-d chunk
    const int rblk = (w & 3) * 16;
    const int wn2  = (w >> 2) * 64;

    const bool gate_wave = ((w & 3) == 0);   // waves 0 and 4

    // ---- preload biases into registers (no global scalar loads in hot loops)
    float b1vA[4], b1vS[4], b1vB[4];
#pragma unroll
    for (int j = 0; j < 4; ++j) {
        int c = wn + j * 16 + lrow;
        b1vA[j] = b1A[c]; b1vS[j] = b1S[c]; b1vB[j] = b1B[c];
    }
    float bgv0 = (lrow < 8)  ? bgA[lrow] : 0.0f;
    float bgv1 = (lrow < 12) ? bgS[lrow] : 0.0f;
    float bgv2 = (lrow < 8)  ? bgB[lrow] : 0.0f;

    // ------------------------------------------------------------------
    // staging helpers (all global_load_lds; uniform instr counts per wave:
    //   per step: W(2) + Gs(1, redundant all-waves) + X(1) = 4)
    // ------------------------------------------------------------------
    auto stage_x = [&](int t) {          // 8KB fp32 x-tile, 512 segs, 1/thread
        int g = t >> 5, k0 = (t & 31) * 32;
        const float* xg = (g == 0) ? xA : ((g == 1) ? xS : xB);
        int s = tid;
        int m = s >> 3, slot = s & 7;
        int seg = slot ^ (m & 7);
        load_lds16(xg + (size_t)(row0 + m) * FF + k0 + seg * 4,
                   Xs + (size_t)(t % 3) * 2048 + s * 4);
    };
    auto stage_w = [&](int t) {          // 16KB f16 W1-tile, 1024 segs, 2/thread
        int g = t >> 5, k0 = (t & 31) * 32;
        const f16* wg = Wp + (size_t)g * 262144;
#pragma unroll
        for (int r = 0; r < 2; ++r) {
            int s = r * 512 + tid;
            int m = s >> 2, slot = s & 3;
            int seg = slot ^ ((m >> 1) & 3);
            load_lds16(wg + (size_t)m * FF + k0 + seg * 8,
                       Ws + (size_t)(t & 1) * 8192 + s * 8);
        }
    };
    auto stage_g = [&](int t) {          // 1KB gate tile; all waves redundantly
        int g = t >> 5, k0 = (t & 31) * 32;
        load_lds16(Gp + (size_t)g * 16384 + (size_t)(lane >> 2) * 1024 + k0 + (lane & 3) * 8,
                   Gs + (size_t)(t & 1) * 512 + lane * 8);
    };

    // ------------------------------------------------------------------
    // Layer-1: 96 flat k-steps (3 groups x 32), pipelined.
    // ------------------------------------------------------------------
    f32x4 acc[2][4] = {};
    f32x4 gacc[2] = {};
    f32x4 gsvA[2], gsvS[2], gsvB[2];

    auto h_write = [&](int g, const float (&bv)[4]) {
        f16* hb = hls + g * 16384;
#pragma unroll
        for (int j = 0; j < 4; ++j) {
            int col = wn + j * 16 + lrow;
            float bias = bv[j];
#pragma unroll
            for (int i = 0; i < 2; ++i)
#pragma unroll
                for (int r = 0; r < 4; ++r) {
                    int row = wm + i * 16 + quad * 4 + r;
                    float v = fmaxf(acc[i][j][r] + bias, 0.0f);
                    hb[row * 256 + (col ^ ((row & 7) << 3))] = (f16)v;
                }
        }
    };

    // prologue: X(0); W(0),Gs(0); X(1)
    stage_x(0);
    __builtin_amdgcn_sched_barrier(0);
    stage_w(0);
    __builtin_amdgcn_sched_barrier(0);
    stage_g(0);
    __builtin_amdgcn_sched_barrier(0);
    stage_x(1);
    __builtin_amdgcn_sched_barrier(0);

    for (int t = 0; t < 96; ++t) {
        int t1 = t + 1;
        int t2 = t + 2;
        if (t < 95) {
            stage_w(t1);
            __builtin_amdgcn_sched_barrier(0);
            stage_g(t1);
            __builtin_amdgcn_sched_barrier(0);
        }
        if (t < 94) {
            stage_x(t2);
            __builtin_amdgcn_sched_barrier(0);
        }
        // steady queue per wave: [X(t),W(t)x2,Gs(t), X(t+1),W(t+1)x2,Gs(t+1),X(t+2)]
        // retire through Gs(t), keep 5 newest in flight.
        if (t < 94)      { asm volatile("s_waitcnt vmcnt(5)" ::: "memory"); }
        else if (t == 94){ asm volatile("s_waitcnt vmcnt(4)" ::: "memory"); }
        else             { asm volatile("s_waitcnt vmcnt(0)" ::: "memory"); }
        __builtin_amdgcn_sched_barrier(0);
        __builtin_amdgcn_s_barrier();
        __builtin_amdgcn_sched_barrier(0);

        // compute step t
        {
            const float* xb = Xs + (t % 3) * 2048;
            const f16* wb = Ws + (t & 1) * 8192;
            f16x8 af[2], bfr[4];
#pragma unroll
            for (int i = 0; i < 2; ++i) {
                int m = wm + i * 16 + lrow;
                const float* rp = xb + m * 32;
                int s0 = (2 * quad) ^ (m & 7);
                float4 lo = *(const float4*)(rp + s0 * 4);
                float4 hi = *(const float4*)(rp + (s0 ^ 1) * 4);
                af[i] = pack8(lo, hi);
            }
#pragma unroll
            for (int j = 0; j < 4; ++j) {
                int n = wn + j * 16 + lrow;
                int slot = quad ^ ((n >> 1) & 3);
                bfr[j] = *(const f16x8*)(wb + n * 32 + slot * 8);
            }
#pragma unroll
            for (int i = 0; i < 2; ++i)
#pragma unroll
                for (int j = 0; j < 4; ++j)
                    acc[i][j] = __builtin_amdgcn_mfma_f32_16x16x32_f16(af[i], bfr[j], acc[i][j], 0, 0, 0);
            if (gate_wave) {
                f16x8 gb = *(const f16x8*)(Gs + (t & 1) * 512 + lrow * 32 + quad * 8);
#pragma unroll
                for (int i = 0; i < 2; ++i)
                    gacc[i] = __builtin_amdgcn_mfma_f32_16x16x32_f16(af[i], gb, gacc[i], 0, 0, 0);
            }
        }

        if ((t & 31) == 31) {          // group boundary: h += bias, relu, -> LDS
            int g = t >> 5;
            if (g == 0)      { h_write(0, b1vA); if (gate_wave) { gsvA[0] = gacc[0]; gsvA[1] = gacc[1]; } }
            else if (g == 1) { h_write(1, b1vS); if (gate_wave) { gsvS[0] = gacc[0]; gsvS[1] = gacc[1]; } }
            else             { h_write(2, b1vB); if (gate_wave) { gsvB[0] = gacc[0]; gsvB[1] = gacc[1]; } }
#pragma unroll
            for (int i = 0; i < 2; ++i) {
#pragma unroll
                for (int j = 0; j < 4; ++j) acc[i][j] = (f32x4){0.f, 0.f, 0.f, 0.f};
                gacc[i] = (f32x4){0.f, 0.f, 0.f, 0.f};
            }
        }

        asm volatile("s_waitcnt lgkmcnt(0)" ::: "memory");
        __builtin_amdgcn_sched_barrier(0);
        __builtin_amdgcn_s_barrier();
        __builtin_amdgcn_sched_barrier(0);
    }

    // ------------------------------------------------------------------
    // l2 prologue: b2 -> LDS, W2 chunk 0 -> buf 0, softmax -> gsh
    // ------------------------------------------------------------------
    auto stage_w2 = [&](int c, int buf) {   // 16KB chunk, 1024 segs, 2/thread
        int p = c >> 1, dh = c & 1;
        int gi = p >> 2, e = p & 3;
        const f16* w2 = W2T + (size_t)(gi * 4 + e) * 16384 + (size_t)dh * 8192;
#pragma unroll
        for (int r = 0; r < 2; ++r) {
            int s = r * 512 + tid;
            int m = s >> 3, slot = s & 7;
            int seg = slot ^ (m & 7);
            load_lds16(w2 + (size_t)m * 64 + seg * 8,
                       W2s + (size_t)buf * 8192 + s * 8);
        }
    };

    {
        const float* s1 = (tid < 256) ? (b2A + tid * 4) : (b2S + (tid - 256) * 4);
        load_lds16(s1, b2s + tid * 4);
        __builtin_amdgcn_sched_barrier(0);
        if (tid < 256) load_lds16(b2B + tid * 4, b2s + 2048 + tid * 4);
        __builtin_amdgcn_sched_barrier(0);
    }
    stage_w2(0, 0);
    __builtin_amdgcn_sched_barrier(0);

    if (gate_wave) {   // softmax over stashed logits; write gates to gsh
        auto softmax_store = [&](const f32x4 (&gsv)[2], float bgc, int ng, int goff) {
            int c = lrow;
            bool valid = (c < ng);
#pragma unroll
            for (int i = 0; i < 2; ++i)
#pragma unroll
                for (int r = 0; r < 4; ++r) {
                    int row = wm + i * 16 + quad * 4 + r;
                    float logit = valid ? (gsv[i][r] + bgc) : -1e30f;
                    float mx = logit;
#pragma unroll
                    for (int m = 1; m < 16; m <<= 1) mx = fmaxf(mx, __shfl_xor(mx, m, 16));
                    float ev = valid ? __expf(logit - mx) : 0.0f;
                    float sum = ev;
#pragma unroll
                    for (int m = 1; m < 16; m <<= 1) sum += __shfl_xor(sum, m, 16);
                    if (valid) gsh[row * 28 + goff + c] = ev / sum;
                }
        };
        softmax_store(gsvA, bgv0, 8, 0);
        softmax_store(gsvS, bgv1, 12, 8);
        softmax_store(gsvB, bgv2, 8, 20);
    }
    // retire b2 (and everything older); keep W2(0) in flight.
    asm volatile("s_waitcnt vmcnt(2) lgkmcnt(0)" ::: "memory");
    __builtin_amdgcn_sched_barrier(0);
    __builtin_amdgcn_s_barrier();
    __builtin_amdgcn_sched_barrier(0);

    // ------------------------------------------------------------------
    // l2: 12 distinct (group,expert) pairs x 2 d-half chunks, pipelined.
    // ------------------------------------------------------------------
    f32x4 oA[2][4] = {}, oS[2][4] = {}, oB[2][4] = {};

    for (int p = 0; p < 12; ++p) {
        int gi = p >> 2, e = p & 3;
#pragma unroll
        for (int dh = 0; dh < 2; ++dh) {
            int c = p * 2 + dh;
            if (c < 23) {
                stage_w2(c + 1, dh ^ 1);
                __builtin_amdgcn_sched_barrier(0);
                asm volatile("s_waitcnt vmcnt(2)" ::: "memory");
            } else {
                asm volatile("s_waitcnt vmcnt(0)" ::: "memory");
            }
            __builtin_amdgcn_sched_barrier(0);
            __builtin_amdgcn_s_barrier();
            __builtin_amdgcn_sched_barrier(0);

            float bias[4];
#pragma unroll
            for (int j = 0; j < 4; ++j)
                bias[j] = b2s[gi * 1024 + e * 256 + dh * 128 + wn2 + j * 16 + lrow];

            const f16* wb = W2s + dh * 8192;
            f32x4 eacc[4] = {};
#pragma unroll
            for (int kk = 0; kk < 2; ++kk) {
                int row = rblk + lrow;
                int u = (kk * 32 + quad * 8) ^ ((row & 7) << 3);
                f16x8 af = *(const f16x8*)(hls + gi * 16384 + row * 256 + e * 64 + u);
                f16x8 bfr[4];
#pragma unroll
                for (int j = 0; j < 4; ++j) {
                    int n = wn2 + j * 16 + lrow;
                    int slot = (kk * 4 + quad) ^ (n & 7);
                    bfr[j] = *(const f16x8*)(wb + n * 64 + slot * 8);
                }
#pragma unroll
                for (int j = 0; j < 4; ++j)
                    eacc[j] = __builtin_amdgcn_mfma_f32_16x16x32_f16(af, bfr[j], eacc[j], 0, 0, 0);
            }

            // oacc += gate[row] * relu(eacc + b2)
#pragma unroll
            for (int r = 0; r < 4; ++r) {
                int row = rblk + quad * 4 + r;
                float ga = 0.f, gs = 0.f, gb = 0.f;
                if (gi == 0)      { ga = gsh[row * 28 + e];      gs = gsh[row * 28 + 8 + e]; }
                else if (gi == 1) { ga = gsh[row * 28 + 4 + e];  gs = gsh[row * 28 + 12 + e]; gb = gsh[row * 28 + 24 + e]; }
                else              { gs = gsh[row * 28 + 16 + e]; gb = gsh[row * 28 + 20 + e]; }
#pragma unroll
                for (int j = 0; j < 4; ++j) {
                    float v = fmaxf(eacc[j][r] + bias[j], 0.0f);
                    if (gi == 0)      { oA[dh][j][r] += ga * v; oS[dh][j][r] += gs * v; }
                    else if (gi == 1) { oA[dh][j][r] += ga * v; oS[dh][j][r] += gs * v; oB[dh][j][r] += gb * v; }
                    else              { oS[dh][j][r] += gs * v; oB[dh][j][r] += gb * v; }
                }
            }

            asm volatile("s_waitcnt lgkmcnt(0)" ::: "memory");
            __builtin_amdgcn_sched_barrier(0);
            __builtin_amdgcn_s_barrier();
            __builtin_amdgcn_sched_barrier(0);
        }
    }

    // epilogue: write the three outputs
#pragma unroll
    for (int dh = 0; dh < 2; ++dh)
#pragma unroll
        for (int j = 0; j < 4; ++j) {
            int d = dh * 128 + wn2 + j * 16 + lrow;
#pragma unroll
            for (int r = 0; r < 4; ++r) {
                int row = row0 + rblk + quad * 4 + r;
                out[((size_t)0 * BB + row) * 256 + d] = oA[dh][j][r];
                out[((size_t)1 * BB + row) * 256 + d] = oS[dh][j][r];
                out[((size_t)2 * BB + row) * 256 + d] = oB[dh][j][r];
            }
        }
}

// ---------------------------------------------------------------------------
extern "C" void kernel_launch(void* const* d_in, const int* in_sizes, int n_in,
                              void* d_out, int out_size, void* d_ws, size_t ws_size,
                              hipStream_t stream)
{
    (void)in_sizes; (void)n_in; (void)out_size; (void)ws_size;

    const float* xA  = (const float*)d_in[0];
    const float* xS  = (const float*)d_in[1];
    const float* xB  = (const float*)d_in[2];
    const float* W1A = (const float*)d_in[3];
    const float* b1A = (const float*)d_in[4];
    const float* W2A = (const float*)d_in[5];
    const float* b2A = (const float*)d_in[6];
    const float* W1S = (const float*)d_in[7];
    const float* b1S = (const float*)d_in[8];
    const float* W2S = (const float*)d_in[9];
    const float* b2S = (const float*)d_in[10];
    const float* W1B = (const float*)d_in[11];
    const float* b1B = (const float*)d_in[12];
    const float* W2B = (const float*)d_in[13];
    const float* b2B = (const float*)d_in[14];
    const float* WgA = (const float*)d_in[15];
    const float* bgA = (const float*)d_in[16];
    const float* WgB = (const float*)d_in[17];
    const float* bgB = (const float*)d_in[18];
    const float* WgS = (const float*)d_in[19];
    const float* bgS = (const float*)d_in[20];

    char* ws = (char*)d_ws;
    f16* Wp  = (f16*)(ws);                 // 1,572,864 B
    f16* W2T = (f16*)(ws + 0x180000);      //   393,216 B
    f16* Gp  = (f16*)(ws + 0x1E0000);      //    98,304 B

    pack_kernel<<<4032, 256, 0, stream>>>(W1A, W1S, W1B, W2A, W2S, W2B,
                                          WgA, WgS, WgB, Wp, W2T, Gp);
    fused_kernel<<<256, 512, 159744, stream>>>(
        xA, xS, xB, b1A, b1S, b1B, bgA, bgS, bgB, b2A, b2S, b2B,
        Wp, Gp, W2T, (float*)d_out);
}